// Round 15
// baseline (22.127 us; speedup 1.0000x reference)
//
#include <hip/hip_runtime.h>

// VectorGauntTensorProduct — factored algebraic collapse, 2-launch structure.
// r15 = r14 consolidated to 4 samples/block (512 blocks):
//   - staging (Ts/Vs) instruction cost per sample halved
//   - stage A: thread=(t,row-pair), T-chunk amortized over 2 rows
//   - stage B: V-hoist amortized over 12 rows
//   - LDS 64,304 B (< 64 KB cap), 2 blocks/CU, all 512 co-resident.
//
// T[t,pq]  = sum_g wq[g] Yin[g,s] Yin[g,sp] Yout[g,t]       (25x100, block-padded)
// V[lt,b,d]= sum_c Wx[ls,c] Wy[lsp,c] Wz[lt,c,d]            (stride-292 rows)
// P[row,pq]= x[n,a,s] y[n,b,sp] - x[n,b,s] y[n,a,sp]        (row = ni*3+v)
// Z[row,t,b] = sum_{pq in block b} P[row,pq] T[t,pq]
// out[n,d,v,t] = sum_b Z[row,t,b] V[l(t),b,d]
//
// Padded block layout: b = ls*3+lsp, sizes {1,3,5,3,9,15,5,15,25} padded to
// {4,4,8,4,12,16,8,16,28}, starts {0,4,8,16,20,32,48,56,72}, total 100.
// Pads are 0.0 in BOTH T and P. V stride 292 de-aliases lt bank groups.
//
// BUG HISTORY: r4 overlay race; r4-r6 `if(tid<N)` staging bug (STRIDED loops
// only). r9->r10: no direct scatter stores — stage in LDS, store coalesced f4.
// r10->r11: keep all blocks co-resident (one latency round). r12: don't trade
// LDS data for LDS instructions. r13: >=3 active waves/block per phase; never
// runtime-index a register array (rule #20 -> scratch).

#define GG 380

__device__ __forceinline__ bool decode2(int pq, int& s, int& sp) {
    int b, off;
    if (pq < 16) {
        if (pq < 4)       { b = 0; off = pq; }
        else if (pq < 8)  { b = 1; off = pq - 4; }
        else              { b = 2; off = pq - 8; }
    } else if (pq < 48) {
        if (pq < 20)      { b = 3; off = pq - 16; }
        else if (pq < 32) { b = 4; off = pq - 20; }
        else              { b = 5; off = pq - 32; }
    } else {
        if (pq < 56)      { b = 6; off = pq - 48; }
        else if (pq < 72) { b = 7; off = pq - 56; }
        else              { b = 8; off = pq - 72; }
    }
    int ls = b / 3, lsp = b % 3, w = 2 * lsp + 1;
    if (off >= (2 * ls + 1) * w) return false;
    s  = ls * ls + off / w;
    sp = lsp * lsp + off % w;
    return true;
}

// ---- precomp: T wave-per-entry + V stride-292 (proven, unchanged)
__global__ __launch_bounds__(256) void precomp(const float* __restrict__ Wx,
                                               const float* __restrict__ Wy,
                                               const float* __restrict__ Wz,
                                               const float* __restrict__ Yin,
                                               const float* __restrict__ Yout,
                                               const float* __restrict__ wq,
                                               float* __restrict__ Tg,
                                               float* __restrict__ Vg) {
    int bid = blockIdx.x;
    if (bid < 625) {
        int W = bid * 4 + (threadIdx.x >> 6);     // 0..2499, = t*100 + pq
        int lane = threadIdx.x & 63;
        int t = W / 100, pq = W % 100;
        int s, sp;
        float acc = 0.f;
        if (decode2(pq, s, sp)) {
#pragma unroll
            for (int i = 0; i < 6; ++i) {
                int g = lane + 64 * i;
                if (g < GG)
                    acc = fmaf(wq[g] * Yin[g * 9 + s],
                               Yin[g * 9 + sp] * Yout[g * 25 + t], acc);
            }
        }
#pragma unroll
        for (int m = 32; m; m >>= 1) acc += __shfl_xor(acc, m, 64);
        if (lane == 0) Tg[W] = acc;               // pads write 0
    } else {
        int idx = (bid - 625) * 256 + threadIdx.x;
        if (idx < 1460) {                          // 5 rows * 292 (incl pads)
            int lt = idx / 292, r = idx % 292;
            float acc = 0.f;
            if (r < 288) {
                int b = r / 32, d = r % 32;
                int ls = b / 3, lsp = b % 3;
                for (int c = 0; c < 32; ++c)
                    acc = fmaf(Wx[ls * 32 + c] * Wy[lsp * 32 + c],
                               Wz[lt * 1024 + c * 32 + d], acc);
            }
            Vg[idx] = acc;                         // pad slots -> 0
        }
    }
}

// ---- main: 4 samples/block, 512 blocks, 256 threads, LDS 64,304 B.
// LDS floats: xs[0,108) ys[108,216) Ps[216,1416) Vs[1416,2876) Z[2876,6476)
//             Ts[6476,8976) dead after A | Zout[6476,16076) overlays Ts+fresh.
__global__ __launch_bounds__(256) void gaunt_main(const float* __restrict__ x,
                                                  const float* __restrict__ y,
                                                  const float* __restrict__ Tg,
                                                  const float* __restrict__ Vg,
                                                  float* __restrict__ out) {
    __shared__ __align__(16) float smem[16076];
    float* xs   = smem;            // 108
    float* ys   = smem + 108;      // 108
    float* Ps   = smem + 216;      // 12*100
    float* Vs   = smem + 1416;     // 5*292
    float* Z    = smem + 2876;     // 12*300
    float* Ts   = smem + 6476;     // 25*100 (dead after stage A)
    float* Zout = smem + 6476;     // 9600 (stage B + copy-out only)

    const int tid = threadIdx.x;
    const int n0 = blockIdx.x * 4;

    if (tid < 108)      xs[tid]       = x[n0 * 27 + tid];
    else if (tid < 216) ys[tid - 108] = y[n0 * 27 + tid - 108];
    for (int i = tid; i < 625; i += 256)            // Ts: 2500 floats
        ((float4*)Ts)[i] = ((const float4*)Tg)[i];
    for (int i = tid; i < 365; i += 256)            // Vs: 1460 floats (strided)
        ((float4*)Vs)[i] = ((const float4*)Vg)[i];
    __syncthreads();

    // P[row][100], pads zero; 12 rows
    for (int idx = tid; idx < 1200; idx += 256) {
        int row = idx / 100, pq = idx % 100;
        float v = 0.f;
        int s, sp;
        if (decode2(pq, s, sp)) {
            int ni = row / 3, vv = row % 3;
            int a = (vv == 0) ? 1 : ((vv == 1) ? 2 : 0);
            int b = (vv == 0) ? 2 : ((vv == 1) ? 0 : 1);
            v = xs[ni * 27 + a * 9 + s] * ys[ni * 27 + b * 9 + sp]
              - xs[ni * 27 + b * 9 + s] * ys[ni * 27 + a * 9 + sp];
        }
        Ps[idx] = v;
    }
    __syncthreads();

    // Stage A: 150 threads, thread = (t = tid/6, g = tid%6) -> rows {2g, 2g+1}.
    // T-chunk read once, used for both rows. Statically-indexed accumulators.
#define DOT4B(c, x0, x1) { const float4 tv = T4[c];                         \
        const float4 p0 = P0[c], p1 = P1[c];                                \
        x0 = fmaf(p0.x, tv.x, x0); x0 = fmaf(p0.y, tv.y, x0);               \
        x0 = fmaf(p0.z, tv.z, x0); x0 = fmaf(p0.w, tv.w, x0);               \
        x1 = fmaf(p1.x, tv.x, x1); x1 = fmaf(p1.y, tv.y, x1);               \
        x1 = fmaf(p1.z, tv.z, x1); x1 = fmaf(p1.w, tv.w, x1); }
    if (tid < 150) {
        const int t = tid / 6, g = tid % 6;
        const int r0 = 2 * g, r1 = 2 * g + 1;
        const float4* T4 = (const float4*)(Ts + t * 100);
        const float4* P0 = (const float4*)(Ps + r0 * 100);
        const float4* P1 = (const float4*)(Ps + r1 * 100);
        float u0 = 0.f, u1 = 0.f, u2 = 0.f, u3 = 0.f, u4 = 0.f,
              u5 = 0.f, u6 = 0.f, u7 = 0.f, u8 = 0.f;
        float v0 = 0.f, v1 = 0.f, v2 = 0.f, v3 = 0.f, v4 = 0.f,
              v5 = 0.f, v6 = 0.f, v7 = 0.f, v8 = 0.f;
        DOT4B(0, u0, v0)
        DOT4B(1, u1, v1)
        DOT4B(2, u2, v2)  DOT4B(3, u2, v2)
        DOT4B(4, u3, v3)
        DOT4B(5, u4, v4)  DOT4B(6, u4, v4)  DOT4B(7, u4, v4)
        DOT4B(8, u5, v5)  DOT4B(9, u5, v5)  DOT4B(10, u5, v5) DOT4B(11, u5, v5)
        DOT4B(12, u6, v6) DOT4B(13, u6, v6)
        DOT4B(14, u7, v7) DOT4B(15, u7, v7) DOT4B(16, u7, v7) DOT4B(17, u7, v7)
        DOT4B(18, u8, v8) DOT4B(19, u8, v8) DOT4B(20, u8, v8) DOT4B(21, u8, v8)
        DOT4B(22, u8, v8) DOT4B(23, u8, v8) DOT4B(24, u8, v8)
        float* zp = Z + r0 * 300 + t * 12;
        *(float4*)zp       = make_float4(u0, u1, u2, u3);
        *(float4*)(zp + 4) = make_float4(u4, u5, u6, u7);
        zp[8] = u8;
        zp = Z + r1 * 300 + t * 12;
        *(float4*)zp       = make_float4(v0, v1, v2, v3);
        *(float4*)(zp + 4) = make_float4(v4, v5, v6, v7);
        zp[8] = v8;
    }
#undef DOT4B
    __syncthreads();
    // ---- Ts DEAD from here; Zout (overlaying it) becomes live ----

    // Stage B: 200 threads, thread = (t = tid>>3, dq = tid&7).
    // 9 V-f4 hoisted once, amortized over 12 rows; Z-reads broadcast.
    if (tid < 200) {
        const int t = tid >> 3, dq = tid & 7;
        const int lt = (t >= 16) ? 4 : (t >= 9) ? 3 : (t >= 4) ? 2
                     : (t >= 1) ? 1 : 0;
        const float* vb = Vs + lt * 292 + dq * 4;
        const float4 w0 = *(const float4*)(vb +   0);
        const float4 w1 = *(const float4*)(vb +  32);
        const float4 w2 = *(const float4*)(vb +  64);
        const float4 w3 = *(const float4*)(vb +  96);
        const float4 w4 = *(const float4*)(vb + 128);
        const float4 w5 = *(const float4*)(vb + 160);
        const float4 w6 = *(const float4*)(vb + 192);
        const float4 w7 = *(const float4*)(vb + 224);
        const float4 w8 = *(const float4*)(vb + 256);
#pragma unroll
        for (int row = 0; row < 12; ++row) {
            const float* zp = Z + row * 300 + t * 12;
            const float4 za = *(const float4*)zp;
            const float4 zb = *(const float4*)(zp + 4);
            const float z8 = zp[8];
            float o0 = z8 * w8.x, o1 = z8 * w8.y, o2 = z8 * w8.z, o3 = z8 * w8.w;
            o0 = fmaf(za.x, w0.x, o0); o1 = fmaf(za.x, w0.y, o1);
            o2 = fmaf(za.x, w0.z, o2); o3 = fmaf(za.x, w0.w, o3);
            o0 = fmaf(za.y, w1.x, o0); o1 = fmaf(za.y, w1.y, o1);
            o2 = fmaf(za.y, w1.z, o2); o3 = fmaf(za.y, w1.w, o3);
            o0 = fmaf(za.z, w2.x, o0); o1 = fmaf(za.z, w2.y, o1);
            o2 = fmaf(za.z, w2.z, o2); o3 = fmaf(za.z, w2.w, o3);
            o0 = fmaf(za.w, w3.x, o0); o1 = fmaf(za.w, w3.y, o1);
            o2 = fmaf(za.w, w3.z, o2); o3 = fmaf(za.w, w3.w, o3);
            o0 = fmaf(zb.x, w4.x, o0); o1 = fmaf(zb.x, w4.y, o1);
            o2 = fmaf(zb.x, w4.z, o2); o3 = fmaf(zb.x, w4.w, o3);
            o0 = fmaf(zb.y, w5.x, o0); o1 = fmaf(zb.y, w5.y, o1);
            o2 = fmaf(zb.y, w5.z, o2); o3 = fmaf(zb.y, w5.w, o3);
            o0 = fmaf(zb.z, w6.x, o0); o1 = fmaf(zb.z, w6.y, o1);
            o2 = fmaf(zb.z, w6.z, o2); o3 = fmaf(zb.z, w6.w, o3);
            o0 = fmaf(zb.w, w7.x, o0); o1 = fmaf(zb.w, w7.y, o1);
            o2 = fmaf(zb.w, w7.z, o2); o3 = fmaf(zb.w, w7.w, o3);
            const int zo = (row / 3) * 2400 + (row % 3) * 25 + dq * 300 + t;
            Zout[zo      ] = o0;
            Zout[zo +  75] = o1;
            Zout[zo + 150] = o2;
            Zout[zo + 225] = o3;
        }
    }
    __syncthreads();

    // coalesced copy-out: 9600 floats = 2400 float4, contiguous per block
    float4* og = (float4*)(out + (size_t)n0 * 2400);
    const float4* zo4 = (const float4*)Zout;
    for (int i = tid; i < 2400; i += 256) og[i] = zo4[i];
}

extern "C" void kernel_launch(void* const* d_in, const int* in_sizes, int n_in,
                              void* d_out, int out_size, void* d_ws, size_t ws_size,
                              hipStream_t stream) {
    const float* x    = (const float*)d_in[0];
    const float* y    = (const float*)d_in[1];
    const float* Wx   = (const float*)d_in[2];
    const float* Wy   = (const float*)d_in[3];
    const float* Wz   = (const float*)d_in[4];
    const float* Yin  = (const float*)d_in[5];
    const float* Yout = (const float*)d_in[6];
    const float* wq   = (const float*)d_in[7];
    float* out = (float*)d_out;

    float* Tg = (float*)d_ws;        // 25*100 = 2500 floats
    float* Vg = Tg + 2500;           // 5*292 = 1460 floats (16B-aligned)

    precomp<<<631, 256, 0, stream>>>(Wx, Wy, Wz, Yin, Yout, wq, Tg, Vg);
    gaunt_main<<<512, 256, 0, stream>>>(x, y, Tg, Vg, out);
}

// Round 16
// 20.077 us; speedup vs baseline: 1.1021x; 1.1021x over previous
//
#include <hip/hip_runtime.h>

// VectorGauntTensorProduct — factored algebraic collapse, 2-launch structure.
// r16 = r14 with T and V read DIRECTLY FROM GLOBAL (L1/L2-resident, read-only):
//   - no Ts/Vs staging round-trips
//   - stage-A/B table reads move from the contended LDS pipe to the VMEM pipe
//   - LDS 29.7 KB -> 5 blocks/CU (20 waves/CU), deeper latency hiding.
//
// T[t,pq]  = sum_g wq[g] Yin[g,s] Yin[g,sp] Yout[g,t]       (25x100, block-padded)
// V[lt,b,d]= sum_c Wx[ls,c] Wy[lsp,c] Wz[lt,c,d]            (stride-292 rows)
// P[row,pq]= x[n,a,s] y[n,b,sp] - x[n,b,s] y[n,a,sp]        (row = ni*3+v)
// Z[row,t,b] = sum_{pq in block b} P[row,pq] T[t,pq]
// out[n,d,v,t] = sum_b Z[row,t,b] V[l(t),b,d]
//
// Padded block layout: b = ls*3+lsp, sizes {1,3,5,3,9,15,5,15,25} padded to
// {4,4,8,4,12,16,8,16,28}, starts {0,4,8,16,20,32,48,56,72}, total 100.
// Pads are 0.0 in BOTH T and P.
//
// BUG HISTORY: r4 overlay race; r4-r6 `if(tid<N)` staging bug (STRIDED loops
// only). r9->r10: no direct scatter stores — stage output in LDS, store
// coalesced f4. r12: don't trade LDS data for LDS instructions. r13: >=3
// active waves/block per phase; no runtime-indexed register arrays. r15:
// occupancy (blocks/CU) beats per-instruction savings — keep LDS small.

#define GG 380

__device__ __forceinline__ bool decode2(int pq, int& s, int& sp) {
    int b, off;
    if (pq < 16) {
        if (pq < 4)       { b = 0; off = pq; }
        else if (pq < 8)  { b = 1; off = pq - 4; }
        else              { b = 2; off = pq - 8; }
    } else if (pq < 48) {
        if (pq < 20)      { b = 3; off = pq - 16; }
        else if (pq < 32) { b = 4; off = pq - 20; }
        else              { b = 5; off = pq - 32; }
    } else {
        if (pq < 56)      { b = 6; off = pq - 48; }
        else if (pq < 72) { b = 7; off = pq - 56; }
        else              { b = 8; off = pq - 72; }
    }
    int ls = b / 3, lsp = b % 3, w = 2 * lsp + 1;
    if (off >= (2 * ls + 1) * w) return false;
    s  = ls * ls + off / w;
    sp = lsp * lsp + off % w;
    return true;
}

// ---- precomp: T wave-per-entry + V stride-292 (proven, unchanged)
__global__ __launch_bounds__(256) void precomp(const float* __restrict__ Wx,
                                               const float* __restrict__ Wy,
                                               const float* __restrict__ Wz,
                                               const float* __restrict__ Yin,
                                               const float* __restrict__ Yout,
                                               const float* __restrict__ wq,
                                               float* __restrict__ Tg,
                                               float* __restrict__ Vg) {
    int bid = blockIdx.x;
    if (bid < 625) {
        int W = bid * 4 + (threadIdx.x >> 6);     // 0..2499, = t*100 + pq
        int lane = threadIdx.x & 63;
        int t = W / 100, pq = W % 100;
        int s, sp;
        float acc = 0.f;
        if (decode2(pq, s, sp)) {
#pragma unroll
            for (int i = 0; i < 6; ++i) {
                int g = lane + 64 * i;
                if (g < GG)
                    acc = fmaf(wq[g] * Yin[g * 9 + s],
                               Yin[g * 9 + sp] * Yout[g * 25 + t], acc);
            }
        }
#pragma unroll
        for (int m = 32; m; m >>= 1) acc += __shfl_xor(acc, m, 64);
        if (lane == 0) Tg[W] = acc;               // pads write 0
    } else {
        int idx = (bid - 625) * 256 + threadIdx.x;
        if (idx < 1460) {                          // 5 rows * 292 (incl pads)
            int lt = idx / 292, r = idx % 292;
            float acc = 0.f;
            if (r < 288) {
                int b = r / 32, d = r % 32;
                int ls = b / 3, lsp = b % 3;
                for (int c = 0; c < 32; ++c)
                    acc = fmaf(Wx[ls * 32 + c] * Wy[lsp * 32 + c],
                               Wz[lt * 1024 + c * 32 + d], acc);
            }
            Vg[idx] = acc;                         // pad slots -> 0
        }
    }
}

// ---- main: 2 samples/block, 1024 blocks, 256 threads, LDS 29.7 KB.
// LDS floats: xs[0,108)* ys[108,216)* Ps[216,816) Z[816,2616) Zout[2616,7416)
//             (*54 used each). T/V read from GLOBAL (L1/L2-resident).
__global__ __launch_bounds__(256) void gaunt_main(const float* __restrict__ x,
                                                  const float* __restrict__ y,
                                                  const float* __restrict__ Tg,
                                                  const float* __restrict__ Vg,
                                                  float* __restrict__ out) {
    __shared__ __align__(16) float smem[7416];
    float* xs   = smem;            // 54 used
    float* ys   = smem + 108;      // 54 used
    float* Ps   = smem + 216;      // 6*100
    float* Z    = smem + 816;      // 6*300
    float* Zout = smem + 2616;     // 4800

    const int tid = threadIdx.x;
    const int n0 = blockIdx.x * 2;

    if (tid < 54)       xs[tid]      = x[n0 * 27 + tid];
    else if (tid < 108) ys[tid - 54] = y[n0 * 27 + tid - 54];
    __syncthreads();

    // P[row][100], pads zero
    for (int idx = tid; idx < 600; idx += 256) {
        int row = idx / 100, pq = idx % 100;
        float v = 0.f;
        int s, sp;
        if (decode2(pq, s, sp)) {
            int ni = row / 3, vv = row % 3;
            int a = (vv == 0) ? 1 : ((vv == 1) ? 2 : 0);
            int b = (vv == 0) ? 2 : ((vv == 1) ? 0 : 1);
            v = xs[ni * 27 + a * 9 + s] * ys[ni * 27 + b * 9 + sp]
              - xs[ni * 27 + b * 9 + s] * ys[ni * 27 + a * 9 + sp];
        }
        Ps[idx] = v;
    }
    __syncthreads();

    // Stage A: 150 threads, thread=(t,row); T-f4 from GLOBAL, P-f4 from LDS.
#define DOT4(c, accv) { float4 pv = P4[c], tv = T4[c];                      \
        accv = fmaf(pv.x, tv.x, accv); accv = fmaf(pv.y, tv.y, accv);       \
        accv = fmaf(pv.z, tv.z, accv); accv = fmaf(pv.w, tv.w, accv); }
    if (tid < 150) {
        int t = tid / 6, row = tid % 6;
        const float4* P4 = (const float4*)(Ps + row * 100);
        const float4* T4 = (const float4*)(Tg + t * 100);   // global, L1/L2
        float a0 = 0.f, a1 = 0.f, a2 = 0.f, a3 = 0.f, a4 = 0.f,
              a5 = 0.f, a6 = 0.f, a7 = 0.f, a8 = 0.f;
        DOT4(0, a0)
        DOT4(1, a1)
        DOT4(2, a2)  DOT4(3, a2)
        DOT4(4, a3)
        DOT4(5, a4)  DOT4(6, a4)  DOT4(7, a4)
        DOT4(8, a5)  DOT4(9, a5)  DOT4(10, a5) DOT4(11, a5)
        DOT4(12, a6) DOT4(13, a6)
        DOT4(14, a7) DOT4(15, a7) DOT4(16, a7) DOT4(17, a7)
        DOT4(18, a8) DOT4(19, a8) DOT4(20, a8) DOT4(21, a8)
        DOT4(22, a8) DOT4(23, a8) DOT4(24, a8)
        float* zp = Z + row * 300 + t * 12;
        *(float4*)zp       = make_float4(a0, a1, a2, a3);
        *(float4*)(zp + 4) = make_float4(a4, a5, a6, a7);
        zp[8] = a8;
    }
#undef DOT4
    __syncthreads();

    // Stage B: 200 threads, thread=(t = tid>>3, dq = tid&7); V-f4 from GLOBAL.
    if (tid < 200) {
        const int t = tid >> 3, dq = tid & 7;
        const int lt = (t >= 16) ? 4 : (t >= 9) ? 3 : (t >= 4) ? 2
                     : (t >= 1) ? 1 : 0;
        const float* vb = Vg + lt * 292 + dq * 4;           // global, L1/L2
        const float4 w0 = *(const float4*)(vb +   0);
        const float4 w1 = *(const float4*)(vb +  32);
        const float4 w2 = *(const float4*)(vb +  64);
        const float4 w3 = *(const float4*)(vb +  96);
        const float4 w4 = *(const float4*)(vb + 128);
        const float4 w5 = *(const float4*)(vb + 160);
        const float4 w6 = *(const float4*)(vb + 192);
        const float4 w7 = *(const float4*)(vb + 224);
        const float4 w8 = *(const float4*)(vb + 256);
#pragma unroll
        for (int row = 0; row < 6; ++row) {
            const float* zp = Z + row * 300 + t * 12;
            const float4 za = *(const float4*)zp;
            const float4 zb = *(const float4*)(zp + 4);
            const float z8 = zp[8];
            float o0 = z8 * w8.x, o1 = z8 * w8.y, o2 = z8 * w8.z, o3 = z8 * w8.w;
            o0 = fmaf(za.x, w0.x, o0); o1 = fmaf(za.x, w0.y, o1);
            o2 = fmaf(za.x, w0.z, o2); o3 = fmaf(za.x, w0.w, o3);
            o0 = fmaf(za.y, w1.x, o0); o1 = fmaf(za.y, w1.y, o1);
            o2 = fmaf(za.y, w1.z, o2); o3 = fmaf(za.y, w1.w, o3);
            o0 = fmaf(za.z, w2.x, o0); o1 = fmaf(za.z, w2.y, o1);
            o2 = fmaf(za.z, w2.z, o2); o3 = fmaf(za.z, w2.w, o3);
            o0 = fmaf(za.w, w3.x, o0); o1 = fmaf(za.w, w3.y, o1);
            o2 = fmaf(za.w, w3.z, o2); o3 = fmaf(za.w, w3.w, o3);
            o0 = fmaf(zb.x, w4.x, o0); o1 = fmaf(zb.x, w4.y, o1);
            o2 = fmaf(zb.x, w4.z, o2); o3 = fmaf(zb.x, w4.w, o3);
            o0 = fmaf(zb.y, w5.x, o0); o1 = fmaf(zb.y, w5.y, o1);
            o2 = fmaf(zb.y, w5.z, o2); o3 = fmaf(zb.y, w5.w, o3);
            o0 = fmaf(zb.z, w6.x, o0); o1 = fmaf(zb.z, w6.y, o1);
            o2 = fmaf(zb.z, w6.z, o2); o3 = fmaf(zb.z, w6.w, o3);
            o0 = fmaf(zb.w, w7.x, o0); o1 = fmaf(zb.w, w7.y, o1);
            o2 = fmaf(zb.w, w7.z, o2); o3 = fmaf(zb.w, w7.w, o3);
            const int zo = (row / 3) * 2400 + (row % 3) * 25 + dq * 300 + t;
            Zout[zo      ] = o0;
            Zout[zo +  75] = o1;
            Zout[zo + 150] = o2;
            Zout[zo + 225] = o3;
        }
    }
    __syncthreads();

    // coalesced copy-out: 4800 floats = 1200 float4, contiguous per block
    float4* og = (float4*)(out + (size_t)n0 * 2400);
    const float4* zo4 = (const float4*)Zout;
    for (int i = tid; i < 1200; i += 256) og[i] = zo4[i];
}

extern "C" void kernel_launch(void* const* d_in, const int* in_sizes, int n_in,
                              void* d_out, int out_size, void* d_ws, size_t ws_size,
                              hipStream_t stream) {
    const float* x    = (const float*)d_in[0];
    const float* y    = (const float*)d_in[1];
    const float* Wx   = (const float*)d_in[2];
    const float* Wy   = (const float*)d_in[3];
    const float* Wz   = (const float*)d_in[4];
    const float* Yin  = (const float*)d_in[5];
    const float* Yout = (const float*)d_in[6];
    const float* wq   = (const float*)d_in[7];
    float* out = (float*)d_out;

    float* Tg = (float*)d_ws;        // 25*100 = 2500 floats
    float* Vg = Tg + 2500;           // 5*292 = 1460 floats (16B-aligned)

    precomp<<<631, 256, 0, stream>>>(Wx, Wy, Wz, Yin, Yout, wq, Tg, Vg);
    gaunt_main<<<1024, 256, 0, stream>>>(x, y, Tg, Vg, out);
}